// Round 2
// baseline (659.213 us; speedup 1.0000x reference)
//
#include <hip/hip_runtime.h>
#include <math.h>

#define B_DIM 64
#define C_DIM 270
#define T_DIM 2000
#define O_DIM 270
#define D_DIM 2048

#define CPAD 272
#define OPAD 320

// ws layout in floats
#define EMB_OFF    0                       // 270*2048
#define SCORES_OFF (C_DIM * D_DIM)         // 272*272
#define W_OFF      (SCORES_OFF + CPAD*CPAD)  // 320*272

// -------------------- Kernel A: Fourier embedding --------------------
// emb[c][d], d<1024: cos(loc), d>=1024: sin(loc); loc = px*i + py*j, idx=i*32+j
__global__ void emb_kernel(const float* __restrict__ layout, float* __restrict__ emb) {
    int c = blockIdx.x;  // 0..269
    const float scale = (float)(2.0 * M_PI / 1.4);
    float px = (layout[c * 2 + 0] + 0.2f) * scale;
    float py = (layout[c * 2 + 1] + 0.2f) * scale;
    float* row = emb + (size_t)c * D_DIM;
    for (int q = threadIdx.x; q < 1024; q += blockDim.x) {
        int i = q >> 5, j = q & 31;
        float loc = px * (float)i + py * (float)j;
        float s, co;
        sincosf(loc, &s, &co);
        row[q] = co;
        row[1024 + q] = s;
    }
}

// -------------------- Kernel B1: scores = heads @ emb^T --------------------
// grid (17 o-groups of 16, 16 c-groups of 17); each thread owns 1-2 (o,c) dots
__global__ __launch_bounds__(256) void scores_kernel(const float* __restrict__ heads,
                                                     const float* __restrict__ emb,
                                                     float* __restrict__ scores) {
    __shared__ float h_s[16][257];
    __shared__ float e_s[17][257];
    int o0 = blockIdx.x * 16;
    int c0 = blockIdx.y * 17;
    int tid = threadIdx.x;
    int ro1 = tid / 17, rc1 = tid % 17;
    bool has2 = (tid < 16);              // pairs 256..271
    int p2 = tid + 256;
    int ro2 = p2 / 17, rc2 = p2 % 17;
    float a1 = 0.f, a2 = 0.f;
    for (int d0 = 0; d0 < D_DIM; d0 += 256) {
        __syncthreads();
        for (int e = tid; e < 16 * 256; e += 256) {
            int r = e >> 8, col = e & 255;
            int o = o0 + r; if (o > O_DIM - 1) o = O_DIM - 1;
            h_s[r][col] = heads[(size_t)o * D_DIM + d0 + col];
        }
        for (int e = tid; e < 17 * 256; e += 256) {
            int r = e >> 8, col = e & 255;
            int c = c0 + r; if (c > C_DIM - 1) c = C_DIM - 1;
            e_s[r][col] = emb[(size_t)c * D_DIM + d0 + col];
        }
        __syncthreads();
        #pragma unroll 4
        for (int dd = 0; dd < 256; ++dd) {
            a1 = fmaf(h_s[ro1][dd], e_s[rc1][dd], a1);
            if (has2) a2 = fmaf(h_s[ro2][dd], e_s[rc2][dd], a2);
        }
    }
    scores[(size_t)(o0 + ro1) * CPAD + c0 + rc1] = a1;
    if (has2) scores[(size_t)(o0 + ro2) * CPAD + c0 + rc2] = a2;
}

// -------------------- Kernel B2: softmax over c, write W --------------------
__global__ void softmax_kernel(const float* __restrict__ scores,
                               const float* __restrict__ layout,
                               float* __restrict__ W) {
    int o = blockIdx.x;          // 0..319
    int lane = threadIdx.x;      // 64
    float* Wrow = W + (size_t)o * CPAD;
    if (o >= O_DIM) {
        for (int c = lane; c < CPAD; c += 64) Wrow[c] = 0.f;
        return;
    }
    float v[5]; int cs[5]; int n = 0;
    float m = -INFINITY;
    for (int c = lane; c < C_DIM; c += 64) {
        float s = scores[(size_t)o * CPAD + c];
        bool inv = (layout[c * 2] == -0.1f) && (layout[c * 2 + 1] == -0.1f);
        if (inv) s = -INFINITY;
        v[n] = s; cs[n] = c; n++;
        m = fmaxf(m, s);
    }
    for (int off = 32; off >= 1; off >>= 1) m = fmaxf(m, __shfl_xor(m, off));
    float sum = 0.f;
    for (int k = 0; k < n; ++k) { v[k] = expf(v[k] - m); sum += v[k]; }
    for (int off = 32; off >= 1; off >>= 1) sum += __shfl_xor(sum, off);
    float inv_s = 1.f / sum;
    for (int k = 0; k < n; ++k) Wrow[cs[k]] = v[k] * inv_s;
    if (lane < 2) Wrow[C_DIM + lane] = 0.f;   // zero pad cols 270,271
}

// -------------------- Kernel C: out[b] = W @ x[b] (f32 register-tiled) ------
// grid (16 t-tiles of 128, 5 o-tiles of 64, 64 b); block 256
__global__ __launch_bounds__(256) void merge_kernel(const float* __restrict__ x,
                                                    const float* __restrict__ W,
                                                    float* __restrict__ out) {
    int tb = blockIdx.x, ob = blockIdx.y, b = blockIdx.z;
    int t0 = tb * 128, o0 = ob * 64;
    int tid = threadIdx.x;
    int tq = tid & 15;   // t lane within 16
    int oq = tid >> 4;   // o quad 0..15
    __shared__ float Ws[16][65];   // [cc][o_local], padded
    __shared__ float xs[16][129];  // [cc][t_local], padded
    float acc[4][8];
    #pragma unroll
    for (int i = 0; i < 4; ++i)
        #pragma unroll
        for (int j = 0; j < 8; ++j) acc[i][j] = 0.f;

    const float* xb = x + (size_t)b * C_DIM * T_DIM;

    for (int ck = 0; ck < 17; ++ck) {
        int c0 = ck * 16;
        __syncthreads();
        {   // W chunk: 16c x 64o
            int e = tid;
            #pragma unroll
            for (int k = 0; k < 4; ++k, e += 256) {
                int oL = e >> 4, cc = e & 15;
                Ws[cc][oL] = W[(size_t)(o0 + oL) * CPAD + c0 + cc];
            }
        }
        {   // x chunk: 16c x 128t
            int e = tid;
            #pragma unroll
            for (int k = 0; k < 8; ++k, e += 256) {
                int cL = e >> 7, tL = e & 127;
                int c = c0 + cL; if (c > C_DIM - 1) c = C_DIM - 1;   // W=0 there
                int t = t0 + tL; if (t > T_DIM - 1) t = T_DIM - 1;   // never stored
                xs[cL][tL] = xb[(size_t)c * T_DIM + t];
            }
        }
        __syncthreads();
        #pragma unroll
        for (int cc = 0; cc < 16; ++cc) {
            float wv[4];
            #pragma unroll
            for (int oi = 0; oi < 4; ++oi) wv[oi] = Ws[cc][oq * 4 + oi];
            #pragma unroll
            for (int ti = 0; ti < 8; ++ti) {
                float xv = xs[cc][tq + ti * 16];
                #pragma unroll
                for (int oi = 0; oi < 4; ++oi)
                    acc[oi][ti] = fmaf(wv[oi], xv, acc[oi][ti]);
            }
        }
    }
    // store
    #pragma unroll
    for (int oi = 0; oi < 4; ++oi) {
        int o = o0 + oq * 4 + oi;
        if (o >= O_DIM) continue;
        float* orow = out + ((size_t)b * O_DIM + o) * T_DIM;
        #pragma unroll
        for (int ti = 0; ti < 8; ++ti) {
            int t = t0 + tq + ti * 16;
            if (t < T_DIM) orow[t] = acc[oi][ti];
        }
    }
}

extern "C" void kernel_launch(void* const* d_in, const int* in_sizes, int n_in,
                              void* d_out, int out_size, void* d_ws, size_t ws_size,
                              hipStream_t stream) {
    const float* x      = (const float*)d_in[0];
    const float* layout = (const float*)d_in[1];
    const float* heads  = (const float*)d_in[2];
    float* out = (float*)d_out;
    float* ws  = (float*)d_ws;
    float* emb    = ws + EMB_OFF;
    float* scores = ws + SCORES_OFF;
    float* W      = ws + W_OFF;

    emb_kernel<<<C_DIM, 256, 0, stream>>>(layout, emb);
    scores_kernel<<<dim3(17, 16), 256, 0, stream>>>(heads, emb, scores);
    softmax_kernel<<<OPAD, 64, 0, stream>>>(scores, layout, W);
    merge_kernel<<<dim3(16, 5, 64), 256, 0, stream>>>(x, W, out);
}

// Round 4
// 330.487 us; speedup vs baseline: 1.9947x; 1.9947x over previous
//
#include <hip/hip_runtime.h>
#include <math.h>

typedef float f32x4 __attribute__((ext_vector_type(4)));
typedef short bf16x8 __attribute__((ext_vector_type(8)));

#define SCALE 4.48798950512827605495f  // 2*pi/1.4

// ---- workspace layout (bytes); total 2,854,656 <= proven-available 2,855,936 ----
#define SCORES_OFF 0              // f32 [270][288]  = 311040 B
#define WH_OFF     311040         // bf16 [288][288] = 165888 B
#define WL_OFF     476928         // bf16 [288][288] = 165888 B
#define EMBH_OFF   642816         // bf16 [270][2048] = 1105920 B
#define HEADSH_OFF 1748736        // bf16 [270][2048] = 1105920 B

__device__ __forceinline__ unsigned short bf16rn(float f) {
    unsigned int u = __float_as_uint(f);
    u += 0x7FFFu + ((u >> 16) & 1u);
    return (unsigned short)(u >> 16);
}

// -------- Kernel 1: prep — emb rows (bf16) + heads convert (bf16) --------
__global__ void prep_kernel(const float* __restrict__ layout,
                            const float* __restrict__ heads,
                            unsigned short* __restrict__ embh,
                            unsigned short* __restrict__ headsh) {
    int blk = blockIdx.x;
    if (blk < 270) {
        int c = blk;
        float px = (layout[2 * c] + 0.2f) * SCALE;
        float py = (layout[2 * c + 1] + 0.2f) * SCALE;
        unsigned short* row = embh + (size_t)c * 2048;
        for (int q = threadIdx.x; q < 1024; q += blockDim.x) {
            int i = q >> 5, j = q & 31;
            float loc = px * (float)i + py * (float)j;
            float s, co;
            sincosf(loc, &s, &co);
            row[q] = bf16rn(co);
            row[1024 + q] = bf16rn(s);
        }
    } else {
        int o = blk - 270;
        const float* src = heads + (size_t)o * 2048;
        unsigned short* dst = headsh + (size_t)o * 2048;
        for (int q = threadIdx.x; q < 2048; q += blockDim.x)
            dst[q] = bf16rn(src[q]);
    }
}

// -------- Kernel 2: scores = heads @ emb^T via bf16 MFMA, K-split atomics --------
// grid (9 o-tiles, 9 c-tiles, 8 k-chunks), 64 threads (1 wave)
__global__ __launch_bounds__(64) void scores_kernel(
    const unsigned short* __restrict__ headsh,
    const unsigned short* __restrict__ embh,
    float* __restrict__ scores)
{
    const int ot = blockIdx.x, ct = blockIdx.y, kc = blockIdx.z;
    const int lane = threadIdx.x;
    const int lhi = lane >> 4, llo = lane & 15;
    f32x4 acc[2][2];
    #pragma unroll
    for (int m = 0; m < 2; ++m)
        #pragma unroll
        for (int n = 0; n < 2; ++n) acc[m][n] = (f32x4){0.f, 0.f, 0.f, 0.f};

    const int k0 = kc * 256;
    #pragma unroll
    for (int ks = 0; ks < 8; ++ks) {
        int kk = k0 + ks * 32 + lhi * 8;
        bf16x8 a[2], bb[2];
        #pragma unroll
        for (int m = 0; m < 2; ++m) {
            int row = ot * 32 + m * 16 + llo; if (row > 269) row = 269;
            a[m] = *(const bf16x8*)(headsh + (size_t)row * 2048 + kk);
        }
        #pragma unroll
        for (int n = 0; n < 2; ++n) {
            int crow = ct * 32 + n * 16 + llo; if (crow > 269) crow = 269;
            bb[n] = *(const bf16x8*)(embh + (size_t)crow * 2048 + kk);
        }
        #pragma unroll
        for (int m = 0; m < 2; ++m)
            #pragma unroll
            for (int n = 0; n < 2; ++n)
                acc[m][n] = __builtin_amdgcn_mfma_f32_16x16x32_bf16(a[m], bb[n], acc[m][n], 0, 0, 0);
    }
    #pragma unroll
    for (int m = 0; m < 2; ++m)
        #pragma unroll
        for (int n = 0; n < 2; ++n)
            #pragma unroll
            for (int r = 0; r < 4; ++r) {
                int row = ot * 32 + m * 16 + lhi * 4 + r;
                int col = ct * 32 + n * 16 + llo;
                if (row < 270 && col < 270)
                    atomicAdd(&scores[row * 288 + col], acc[m][n][r]);
            }
}

// -------- Kernel 3: softmax over c; writes Wh/Wl bf16 [288][288] zero-padded --------
__global__ void softmax_kernel(const float* __restrict__ scores,
                               const float* __restrict__ layout,
                               unsigned short* __restrict__ Wh,
                               unsigned short* __restrict__ Wl) {
    int o = blockIdx.x;          // 0..287
    int lane = threadIdx.x;      // 64
    unsigned short* wh = Wh + (size_t)o * 288;
    unsigned short* wl = Wl + (size_t)o * 288;
    if (o >= 270) {
        for (int c = lane; c < 288; c += 64) { wh[c] = 0; wl[c] = 0; }
        return;
    }
    float v[5]; int cs[5]; int n = 0;
    float m = -INFINITY;
    for (int c = lane; c < 270; c += 64) {
        float s = scores[o * 288 + c];
        bool inv = (layout[c * 2] == -0.1f) && (layout[c * 2 + 1] == -0.1f);
        if (inv) s = -INFINITY;
        v[n] = s; cs[n] = c; n++;
        m = fmaxf(m, s);
    }
    for (int off = 32; off >= 1; off >>= 1) m = fmaxf(m, __shfl_xor(m, off));
    float sum = 0.f;
    for (int k = 0; k < n; ++k) { v[k] = expf(v[k] - m); sum += v[k]; }
    for (int off = 32; off >= 1; off >>= 1) sum += __shfl_xor(sum, off);
    float inv_s = 1.f / sum;
    for (int k = 0; k < n; ++k) {
        float w = v[k] * inv_s;
        unsigned int wb = __float_as_uint(w);
        unsigned short hi = (unsigned short)(wb >> 16);         // truncation split
        float whf = __uint_as_float(wb & 0xFFFF0000u);
        wh[cs[k]] = hi;
        wl[cs[k]] = (unsigned short)(__float_as_uint(w - whf) >> 16);
    }
    for (int c = 270 + lane; c < 288; c += 64) { wh[c] = 0; wl[c] = 0; }
}

// -------- Kernel 4: merge — out[b] = W @ x[b], 3-term split-bf16 MFMA --------
// grid (16 t-tiles of 128, 3 o-tiles of 96, 64 b); block 256 (4 waves, 2x2)
__global__ __launch_bounds__(256, 2) void merge_kernel(
    const float* __restrict__ x,
    const unsigned short* __restrict__ Wh,
    const unsigned short* __restrict__ Wl,
    float* __restrict__ out)
{
    __shared__ float xs[2][32][128];
    const int tb = blockIdx.x, ob = blockIdx.y, b = blockIdx.z;
    const int t0 = tb * 128, o0 = ob * 96;
    const int tid = threadIdx.x;
    const int wid = tid >> 6, lane = tid & 63;
    const int wo = (wid >> 1) * 48, wt = (wid & 1) * 64;
    const int lhi = lane >> 4, llo = lane & 15;

    const float* xb = x + (size_t)b * 270 * 2000;
    const float* x_last = x + (size_t)64 * 270 * 2000 - 4;

    f32x4 acc[3][4];
    #pragma unroll
    for (int m = 0; m < 3; ++m)
        #pragma unroll
        for (int n = 0; n < 4; ++n) acc[m][n] = (f32x4){0.f, 0.f, 0.f, 0.f};

    int s_row[4], s_col4[4];
    #pragma unroll
    for (int i = 0; i < 4; ++i) {
        int f = tid + (i << 8);
        s_row[i] = f >> 5;     // 0..31 (c within k-step)
        s_col4[i] = f & 31;    // float4 column
    }
    f32x4 stg[4];

    auto load_tile = [&](int ks) {
        #pragma unroll
        for (int i = 0; i < 4; ++i) {
            int c = ks * 32 + s_row[i];
            if (c > 269) c = 269;                       // W k-pad is zero -> harmless
            const float* p = xb + (size_t)c * 2000 + t0 + (s_col4[i] << 2);
            if (p > x_last) p = x_last;                 // stay in-bounds; masked at store
            stg[i] = *(const f32x4*)p;
        }
    };
    auto store_tile = [&](int buf) {
        #pragma unroll
        for (int i = 0; i < 4; ++i) {
            int cs = s_col4[i] ^ ((s_row[i] >> 2) & 7);  // XOR swizzle (bank-conflict-free)
            *(f32x4*)&xs[buf][s_row[i]][cs << 2] = stg[i];
        }
    };

    load_tile(0);
    store_tile(0);
    __syncthreads();

    for (int ks = 0; ks < 9; ++ks) {
        const int cur = ks & 1;
        if (ks < 8) load_tile(ks + 1);   // global->regs, in flight during compute

        // A fragments straight from global (L2-resident W)
        bf16x8 ah[3], al[3];
        #pragma unroll
        for (int m = 0; m < 3; ++m) {
            int row = o0 + wo + m * 16 + llo;
            size_t off = (size_t)row * 288 + ks * 32 + lhi * 8;
            ah[m] = *(const bf16x8*)(Wh + off);
            al[m] = *(const bf16x8*)(Wl + off);
        }

        #pragma unroll
        for (int nf = 0; nf < 4; ++nf) {
            int tcol = wt + nf * 16 + llo;
            float xr[8];
            #pragma unroll
            for (int j = 0; j < 8; ++j) {
                int k = lhi * 8 + j;
                int cidx = tcol ^ (((k >> 2) & 7) << 2);  // matches write swizzle
                xr[j] = xs[cur][k][cidx];
            }
            // in-register split to bf16 high/low fragments
            union { unsigned int u[4]; bf16x8 v; } bh, bl;
            #pragma unroll
            for (int p = 0; p < 4; ++p) {
                unsigned int u0 = __float_as_uint(xr[2 * p]);
                unsigned int u1 = __float_as_uint(xr[2 * p + 1]);
                bh.u[p] = (u0 >> 16) | (u1 & 0xFFFF0000u);
                float h0 = __uint_as_float(u0 & 0xFFFF0000u);
                float h1 = __uint_as_float(u1 & 0xFFFF0000u);
                unsigned int l0 = __float_as_uint(xr[2 * p] - h0);
                unsigned int l1 = __float_as_uint(xr[2 * p + 1] - h1);
                bl.u[p] = (l0 >> 16) | (l1 & 0xFFFF0000u);
            }
            #pragma unroll
            for (int m = 0; m < 3; ++m) {
                acc[m][nf] = __builtin_amdgcn_mfma_f32_16x16x32_bf16(ah[m], bh.v, acc[m][nf], 0, 0, 0);
                acc[m][nf] = __builtin_amdgcn_mfma_f32_16x16x32_bf16(ah[m], bl.v, acc[m][nf], 0, 0, 0);
                acc[m][nf] = __builtin_amdgcn_mfma_f32_16x16x32_bf16(al[m], bh.v, acc[m][nf], 0, 0, 0);
            }
        }

        if (ks < 8) store_tile(cur ^ 1);  // write other buffer (readers done last barrier)
        __syncthreads();
    }

    // epilogue: D frag -> out; D[row=4*lhi+r][col=llo]
    const size_t ob_base = (size_t)b * 270 * 2000;
    #pragma unroll
    for (int m = 0; m < 3; ++m) {
        #pragma unroll
        for (int r = 0; r < 4; ++r) {
            int orow = o0 + wo + m * 16 + lhi * 4 + r;
            if (orow < 270) {
                float* op = out + ob_base + (size_t)orow * 2000;
                #pragma unroll
                for (int nf = 0; nf < 4; ++nf) {
                    int t = t0 + wt + nf * 16 + llo;
                    if (t < 2000) op[t] = acc[m][nf][r];
                }
            }
        }
    }
}

extern "C" void kernel_launch(void* const* d_in, const int* in_sizes, int n_in,
                              void* d_out, int out_size, void* d_ws, size_t ws_size,
                              hipStream_t stream) {
    const float* x      = (const float*)d_in[0];
    const float* layout = (const float*)d_in[1];
    const float* heads  = (const float*)d_in[2];
    float* out = (float*)d_out;
    char* ws = (char*)d_ws;

    float* scores          = (float*)(ws + SCORES_OFF);
    unsigned short* Wh     = (unsigned short*)(ws + WH_OFF);
    unsigned short* Wl     = (unsigned short*)(ws + WL_OFF);
    unsigned short* embh   = (unsigned short*)(ws + EMBH_OFF);
    unsigned short* headsh = (unsigned short*)(ws + HEADSH_OFF);

    hipMemsetAsync(scores, 0, 270 * 288 * 4, stream);
    prep_kernel<<<540, 256, 0, stream>>>(layout, heads, embh, headsh);
    scores_kernel<<<dim3(9, 9, 8), 64, 0, stream>>>(headsh, embh, scores);
    softmax_kernel<<<288, 64, 0, stream>>>(scores, layout, Wh, Wl);
    merge_kernel<<<dim3(16, 3, 64), 256, 0, stream>>>(x, Wh, Wl, out);
}

// Round 5
// 315.913 us; speedup vs baseline: 2.0867x; 1.0461x over previous
//
#include <hip/hip_runtime.h>
#include <math.h>

typedef float f32x4 __attribute__((ext_vector_type(4)));
typedef short bf16x8 __attribute__((ext_vector_type(8)));

#define SCALE 4.48798950512827605495f  // 2*pi/1.4

// ---- workspace layout (bytes); total 2,854,656 ----
#define SCORES_OFF 0              // f32 [270][288]
#define WH_OFF     311040         // bf16 [288][288]
#define WL_OFF     476928         // bf16 [288][288]
#define EMBH_OFF   642816         // bf16 [270][2048]
#define HEADSH_OFF 1748736        // bf16 [270][2048]

__device__ __forceinline__ unsigned short bf16rn(float f) {
    unsigned int u = __float_as_uint(f);
    u += 0x7FFFu + ((u >> 16) & 1u);
    return (unsigned short)(u >> 16);
}

// -------- Kernel 1: prep — emb rows (bf16) + heads convert (bf16) --------
__global__ void prep_kernel(const float* __restrict__ layout,
                            const float* __restrict__ heads,
                            unsigned short* __restrict__ embh,
                            unsigned short* __restrict__ headsh) {
    int blk = blockIdx.x;
    if (blk < 270) {
        int c = blk;
        float px = (layout[2 * c] + 0.2f) * SCALE;
        float py = (layout[2 * c + 1] + 0.2f) * SCALE;
        unsigned short* row = embh + (size_t)c * 2048;
        for (int q = threadIdx.x; q < 1024; q += blockDim.x) {
            int i = q >> 5, j = q & 31;
            float loc = px * (float)i + py * (float)j;
            float s, co;
            sincosf(loc, &s, &co);
            row[q] = bf16rn(co);
            row[1024 + q] = bf16rn(s);
        }
    } else {
        int o = blk - 270;
        const float* src = heads + (size_t)o * 2048;
        unsigned short* dst = headsh + (size_t)o * 2048;
        for (int q = threadIdx.x; q < 2048; q += blockDim.x)
            dst[q] = bf16rn(src[q]);
    }
}

// -------- Kernel 2: scores = heads @ emb^T, 4-wave k-split + LDS reduce --------
// grid (9 o-tiles, 9 c-tiles), 256 threads
__global__ __launch_bounds__(256) void scores_kernel(
    const unsigned short* __restrict__ headsh,
    const unsigned short* __restrict__ embh,
    float* __restrict__ scores)
{
    __shared__ float red[4][64][16];
    const int ot = blockIdx.x, ct = blockIdx.y;
    const int tid = threadIdx.x;
    const int w = tid >> 6, lane = tid & 63;
    const int lhi = lane >> 4, llo = lane & 15;

    f32x4 acc[2][2];
    #pragma unroll
    for (int m = 0; m < 2; ++m)
        #pragma unroll
        for (int n = 0; n < 2; ++n) acc[m][n] = (f32x4){0.f, 0.f, 0.f, 0.f};

    int arow[2], crow[2];
    #pragma unroll
    for (int m = 0; m < 2; ++m) {
        int r = ot * 32 + m * 16 + llo; arow[m] = (r > 269) ? 269 : r;
        int c = ct * 32 + m * 16 + llo; crow[m] = (c > 269) ? 269 : c;
    }

    for (int s = 0; s < 16; ++s) {
        int kk = w * 512 + s * 32 + lhi * 8;
        bf16x8 a[2], bb[2];
        #pragma unroll
        for (int m = 0; m < 2; ++m)
            a[m] = *(const bf16x8*)(headsh + (size_t)arow[m] * 2048 + kk);
        #pragma unroll
        for (int n = 0; n < 2; ++n)
            bb[n] = *(const bf16x8*)(embh + (size_t)crow[n] * 2048 + kk);
        #pragma unroll
        for (int m = 0; m < 2; ++m)
            #pragma unroll
            for (int n = 0; n < 2; ++n)
                acc[m][n] = __builtin_amdgcn_mfma_f32_16x16x32_bf16(a[m], bb[n], acc[m][n], 0, 0, 0);
    }

    #pragma unroll
    for (int m = 0; m < 2; ++m)
        #pragma unroll
        for (int n = 0; n < 2; ++n)
            #pragma unroll
            for (int r = 0; r < 4; ++r)
                red[w][lane][m * 8 + n * 4 + r] = acc[m][n][r];
    __syncthreads();
    if (w == 0) {
        #pragma unroll
        for (int m = 0; m < 2; ++m)
            #pragma unroll
            for (int n = 0; n < 2; ++n)
                #pragma unroll
                for (int r = 0; r < 4; ++r) {
                    int idx = m * 8 + n * 4 + r;
                    float sum = red[0][lane][idx] + red[1][lane][idx]
                              + red[2][lane][idx] + red[3][lane][idx];
                    int row = ot * 32 + m * 16 + lhi * 4 + r;
                    int col = ct * 32 + n * 16 + llo;
                    if (row < 270 && col < 270)
                        scores[row * 288 + col] = sum;
                }
    }
}

// -------- Kernel 3: softmax over c; writes Wh/Wl bf16 [288][288] zero-padded --------
__global__ void softmax_kernel(const float* __restrict__ scores,
                               const float* __restrict__ layout,
                               unsigned short* __restrict__ Wh,
                               unsigned short* __restrict__ Wl) {
    int o = blockIdx.x;          // 0..287
    int lane = threadIdx.x;      // 64
    unsigned short* wh = Wh + (size_t)o * 288;
    unsigned short* wl = Wl + (size_t)o * 288;
    if (o >= 270) {
        for (int c = lane; c < 288; c += 64) { wh[c] = 0; wl[c] = 0; }
        return;
    }
    float v[5]; int cs[5]; int n = 0;
    float m = -INFINITY;
    for (int c = lane; c < 270; c += 64) {
        float s = scores[o * 288 + c];
        bool inv = (layout[c * 2] == -0.1f) && (layout[c * 2 + 1] == -0.1f);
        if (inv) s = -INFINITY;
        v[n] = s; cs[n] = c; n++;
        m = fmaxf(m, s);
    }
    for (int off = 32; off >= 1; off >>= 1) m = fmaxf(m, __shfl_xor(m, off));
    float sum = 0.f;
    for (int k = 0; k < n; ++k) { v[k] = expf(v[k] - m); sum += v[k]; }
    for (int off = 32; off >= 1; off >>= 1) sum += __shfl_xor(sum, off);
    float inv_s = 1.f / sum;
    for (int k = 0; k < n; ++k) {
        float w = v[k] * inv_s;
        unsigned int wb = __float_as_uint(w);
        unsigned short hi = (unsigned short)(wb >> 16);         // truncation split
        float whf = __uint_as_float(wb & 0xFFFF0000u);
        wh[cs[k]] = hi;
        wl[cs[k]] = (unsigned short)(__float_as_uint(w - whf) >> 16);
    }
    for (int c = 270 + lane; c < 288; c += 64) { wh[c] = 0; wl[c] = 0; }
}

// -------- Kernel 4: merge — out[b] = W @ x[b], 3-term split-bf16 MFMA --------
// block tile: 96 o x 256 t; 4 waves, each: all 6 m-frags x disjoint 64-t slice
// grid (8 t-tiles, 3 o-tiles, 64 b); block 256
__global__ __launch_bounds__(256, 2) void merge_kernel(
    const float* __restrict__ x,
    const unsigned short* __restrict__ Wh,
    const unsigned short* __restrict__ Wl,
    float* __restrict__ out)
{
    __shared__ float xs[2][32][256];
    const int tb = blockIdx.x, ob = blockIdx.y, b = blockIdx.z;
    const int t0 = tb * 256, o0 = ob * 96;
    const int tid = threadIdx.x;
    const int wid = tid >> 6, lane = tid & 63;
    const int wt = wid * 64;
    const int lhi = lane >> 4, llo = lane & 15;

    const float* xb = x + (size_t)b * 270 * 2000;
    const float* x_last = x + (size_t)64 * 270 * 2000 - 4;

    f32x4 acc[6][4];
    #pragma unroll
    for (int m = 0; m < 6; ++m)
        #pragma unroll
        for (int n = 0; n < 4; ++n) acc[m][n] = (f32x4){0.f, 0.f, 0.f, 0.f};

    // staging: iter p -> row = p*4 + wid (0..31), col4 = lane (0..63)
    f32x4 stg[8];
    auto load_tile = [&](int ks) {
        #pragma unroll
        for (int p = 0; p < 8; ++p) {
            int c = ks * 32 + p * 4 + wid;
            if (c > 269) c = 269;                       // W k-pad is zero -> harmless
            const float* ptr = xb + (size_t)c * 2000 + t0 + (lane << 2);
            if (ptr > x_last) ptr = x_last;             // in-bounds; masked at store
            stg[p] = *(const f32x4*)ptr;
        }
    };
    auto store_tile = [&](int buf) {
        #pragma unroll
        for (int p = 0; p < 8; ++p) {
            int row = p * 4 + wid;
            int cs = lane ^ ((row >> 2) & 7);           // XOR swizzle
            *(f32x4*)&xs[buf][row][cs << 2] = stg[p];
        }
    };

    load_tile(0);
    store_tile(0);
    __syncthreads();

    for (int ks = 0; ks < 9; ++ks) {
        const int cur = ks & 1;
        if (ks < 8) load_tile(ks + 1);   // next tile global->regs during compute

        // A fragments (Wh/Wl rows o0..o0+95) straight from L1/L2
        bf16x8 ah[6], al[6];
        #pragma unroll
        for (int m = 0; m < 6; ++m) {
            int row = o0 + m * 16 + llo;
            size_t off = (size_t)row * 288 + ks * 32 + lhi * 8;
            ah[m] = *(const bf16x8*)(Wh + off);
            al[m] = *(const bf16x8*)(Wl + off);
        }

        #pragma unroll
        for (int nf = 0; nf < 4; ++nf) {
            int tcol = wt + nf * 16 + llo;
            float xr[8];
            #pragma unroll
            for (int j = 0; j < 8; ++j) {
                int k = lhi * 8 + j;
                int cidx = tcol ^ (((k >> 2) & 7) << 2);  // matches write swizzle
                xr[j] = xs[cur][k][cidx];
            }
            // in-register split to bf16 high/low fragments
            union { unsigned int u[4]; bf16x8 v; } bh, bl;
            #pragma unroll
            for (int p = 0; p < 4; ++p) {
                unsigned int u0 = __float_as_uint(xr[2 * p]);
                unsigned int u1 = __float_as_uint(xr[2 * p + 1]);
                bh.u[p] = (u0 >> 16) | (u1 & 0xFFFF0000u);
                float h0 = __uint_as_float(u0 & 0xFFFF0000u);
                float h1 = __uint_as_float(u1 & 0xFFFF0000u);
                unsigned int l0 = __float_as_uint(xr[2 * p] - h0);
                unsigned int l1 = __float_as_uint(xr[2 * p + 1] - h1);
                bl.u[p] = (l0 >> 16) | (l1 & 0xFFFF0000u);
            }
            #pragma unroll
            for (int m = 0; m < 6; ++m) {
                acc[m][nf] = __builtin_amdgcn_mfma_f32_16x16x32_bf16(ah[m], bh.v, acc[m][nf], 0, 0, 0);
                acc[m][nf] = __builtin_amdgcn_mfma_f32_16x16x32_bf16(ah[m], bl.v, acc[m][nf], 0, 0, 0);
                acc[m][nf] = __builtin_amdgcn_mfma_f32_16x16x32_bf16(al[m], bh.v, acc[m][nf], 0, 0, 0);
            }
        }

        if (ks < 8) store_tile(cur ^ 1);  // other buffer (readers done at last barrier)
        __syncthreads();
    }

    // epilogue: D frag -> out; D[row=4*lhi+r][col=llo]
    const size_t ob_base = (size_t)b * 270 * 2000;
    #pragma unroll
    for (int m = 0; m < 6; ++m) {
        #pragma unroll
        for (int r = 0; r < 4; ++r) {
            int orow = o0 + m * 16 + lhi * 4 + r;
            if (orow < 270) {
                float* op = out + ob_base + (size_t)orow * 2000;
                #pragma unroll
                for (int nf = 0; nf < 4; ++nf) {
                    int t = t0 + wt + nf * 16 + llo;
                    if (t < 2000) op[t] = acc[m][nf][r];
                }
            }
        }
    }
}

extern "C" void kernel_launch(void* const* d_in, const int* in_sizes, int n_in,
                              void* d_out, int out_size, void* d_ws, size_t ws_size,
                              hipStream_t stream) {
    const float* x      = (const float*)d_in[0];
    const float* layout = (const float*)d_in[1];
    const float* heads  = (const float*)d_in[2];
    float* out = (float*)d_out;
    char* ws = (char*)d_ws;

    float* scores          = (float*)(ws + SCORES_OFF);
    unsigned short* Wh     = (unsigned short*)(ws + WH_OFF);
    unsigned short* Wl     = (unsigned short*)(ws + WL_OFF);
    unsigned short* embh   = (unsigned short*)(ws + EMBH_OFF);
    unsigned short* headsh = (unsigned short*)(ws + HEADSH_OFF);

    prep_kernel<<<540, 256, 0, stream>>>(layout, heads, embh, headsh);
    scores_kernel<<<dim3(9, 9), 256, 0, stream>>>(headsh, embh, scores);
    softmax_kernel<<<288, 64, 0, stream>>>(scores, layout, Wh, Wl);
    merge_kernel<<<dim3(8, 3, 64), 256, 0, stream>>>(x, Wh, Wl, out);
}

// Round 6
// 314.053 us; speedup vs baseline: 2.0991x; 1.0059x over previous
//
#include <hip/hip_runtime.h>
#include <math.h>

typedef float f32x4 __attribute__((ext_vector_type(4)));
typedef short bf16x8 __attribute__((ext_vector_type(8)));
typedef unsigned int u32;

#define SCALE 4.48798950512827605495f  // 2*pi/1.4

// ---- workspace layout (bytes); total 2,854,656 ----
#define SCORES_OFF 0              // f32 [270][288]
#define WH_OFF     311040         // bf16 [288][288]
#define WL_OFF     476928         // bf16 [288][288]
#define EMBH_OFF   642816         // bf16 [270][2048]
#define HEADSH_OFF 1748736        // bf16 [270][2048]

__device__ __forceinline__ unsigned short bf16rn(float f) {
    unsigned int u = __float_as_uint(f);
    u += 0x7FFFu + ((u >> 16) & 1u);
    return (unsigned short)(u >> 16);
}

// -------- Kernel 1: prep — emb rows (bf16) + heads convert (bf16) --------
__global__ void prep_kernel(const float* __restrict__ layout,
                            const float* __restrict__ heads,
                            unsigned short* __restrict__ embh,
                            unsigned short* __restrict__ headsh) {
    int blk = blockIdx.x;
    if (blk < 270) {
        int c = blk;
        float px = (layout[2 * c] + 0.2f) * SCALE;
        float py = (layout[2 * c + 1] + 0.2f) * SCALE;
        unsigned short* row = embh + (size_t)c * 2048;
        for (int q = threadIdx.x; q < 1024; q += blockDim.x) {
            int i = q >> 5, j = q & 31;
            float loc = px * (float)i + py * (float)j;
            float s, co;
            sincosf(loc, &s, &co);
            row[q] = bf16rn(co);
            row[1024 + q] = bf16rn(s);
        }
    } else {
        int o = blk - 270;
        const float* src = heads + (size_t)o * 2048;
        unsigned short* dst = headsh + (size_t)o * 2048;
        for (int q = threadIdx.x; q < 2048; q += blockDim.x)
            dst[q] = bf16rn(src[q]);
    }
}

// -------- Kernel 2: scores = heads @ emb^T, 4-wave k-split + LDS reduce --------
// grid (9 o-tiles, 9 c-tiles), 256 threads
__global__ __launch_bounds__(256) void scores_kernel(
    const unsigned short* __restrict__ headsh,
    const unsigned short* __restrict__ embh,
    float* __restrict__ scores)
{
    __shared__ float red[4][64][16];
    const int ot = blockIdx.x, ct = blockIdx.y;
    const int tid = threadIdx.x;
    const int w = tid >> 6, lane = tid & 63;
    const int lhi = lane >> 4, llo = lane & 15;

    f32x4 acc[2][2];
    #pragma unroll
    for (int m = 0; m < 2; ++m)
        #pragma unroll
        for (int n = 0; n < 2; ++n) acc[m][n] = (f32x4){0.f, 0.f, 0.f, 0.f};

    int arow[2], crow[2];
    #pragma unroll
    for (int m = 0; m < 2; ++m) {
        int r = ot * 32 + m * 16 + llo; arow[m] = (r > 269) ? 269 : r;
        int c = ct * 32 + m * 16 + llo; crow[m] = (c > 269) ? 269 : c;
    }

    for (int s = 0; s < 16; ++s) {
        int kk = w * 512 + s * 32 + lhi * 8;
        bf16x8 a[2], bb[2];
        #pragma unroll
        for (int m = 0; m < 2; ++m)
            a[m] = *(const bf16x8*)(headsh + (size_t)arow[m] * 2048 + kk);
        #pragma unroll
        for (int n = 0; n < 2; ++n)
            bb[n] = *(const bf16x8*)(embh + (size_t)crow[n] * 2048 + kk);
        #pragma unroll
        for (int m = 0; m < 2; ++m)
            #pragma unroll
            for (int n = 0; n < 2; ++n)
                acc[m][n] = __builtin_amdgcn_mfma_f32_16x16x32_bf16(a[m], bb[n], acc[m][n], 0, 0, 0);
    }

    #pragma unroll
    for (int m = 0; m < 2; ++m)
        #pragma unroll
        for (int n = 0; n < 2; ++n)
            #pragma unroll
            for (int r = 0; r < 4; ++r)
                red[w][lane][m * 8 + n * 4 + r] = acc[m][n][r];
    __syncthreads();
    if (w == 0) {
        #pragma unroll
        for (int m = 0; m < 2; ++m)
            #pragma unroll
            for (int n = 0; n < 2; ++n)
                #pragma unroll
                for (int r = 0; r < 4; ++r) {
                    int idx = m * 8 + n * 4 + r;
                    float sum = red[0][lane][idx] + red[1][lane][idx]
                              + red[2][lane][idx] + red[3][lane][idx];
                    int row = ot * 32 + m * 16 + lhi * 4 + r;
                    int col = ct * 32 + n * 16 + llo;
                    if (row < 270 && col < 270)
                        scores[row * 288 + col] = sum;
                }
    }
}

// -------- Kernel 3: softmax over c; writes Wh/Wl bf16 [288][288] zero-padded --------
__global__ void softmax_kernel(const float* __restrict__ scores,
                               const float* __restrict__ layout,
                               unsigned short* __restrict__ Wh,
                               unsigned short* __restrict__ Wl) {
    int o = blockIdx.x;          // 0..287
    int lane = threadIdx.x;      // 64
    unsigned short* wh = Wh + (size_t)o * 288;
    unsigned short* wl = Wl + (size_t)o * 288;
    if (o >= 270) {
        for (int c = lane; c < 288; c += 64) { wh[c] = 0; wl[c] = 0; }
        return;
    }
    float v[5]; int cs[5]; int n = 0;
    float m = -INFINITY;
    for (int c = lane; c < 270; c += 64) {
        float s = scores[o * 288 + c];
        bool inv = (layout[c * 2] == -0.1f) && (layout[c * 2 + 1] == -0.1f);
        if (inv) s = -INFINITY;
        v[n] = s; cs[n] = c; n++;
        m = fmaxf(m, s);
    }
    for (int off = 32; off >= 1; off >>= 1) m = fmaxf(m, __shfl_xor(m, off));
    float sum = 0.f;
    for (int k = 0; k < n; ++k) { v[k] = expf(v[k] - m); sum += v[k]; }
    for (int off = 32; off >= 1; off >>= 1) sum += __shfl_xor(sum, off);
    float inv_s = 1.f / sum;
    for (int k = 0; k < n; ++k) {
        float w = v[k] * inv_s;
        unsigned int wb = __float_as_uint(w);
        unsigned short hi = (unsigned short)(wb >> 16);         // truncation split
        float whf = __uint_as_float(wb & 0xFFFF0000u);
        wh[cs[k]] = hi;
        wl[cs[k]] = (unsigned short)(__float_as_uint(w - whf) >> 16);
    }
    for (int c = 270 + lane; c < 288; c += 64) { wh[c] = 0; wl[c] = 0; }
}

// -------- Kernel 4: merge — out[b] = W @ x[b], 3-term split-bf16 MFMA --------
// block tile: 96 o x 256 t; 4 waves, each: all 6 m-frags x disjoint 64-t slice
// x staged via global_load_lds (width 16) with pre-swizzled per-lane source.
// grid (8 t-tiles, 3 o-tiles, 64 b); block 256. LDS 64KB -> 2 blocks/CU.
__global__ __launch_bounds__(256) void merge_kernel(
    const float* __restrict__ x,
    const unsigned short* __restrict__ Wh,
    const unsigned short* __restrict__ Wl,
    float* __restrict__ out)
{
    __shared__ float xs[2][32][256];
    const int tb = blockIdx.x, ob = blockIdx.y, b = blockIdx.z;
    const int t0 = tb * 256, o0 = ob * 96;
    const int tid = threadIdx.x;
    const int wid = tid >> 6, lane = tid & 63;
    const int wt = wid * 64;
    const int lhi = lane >> 4, llo = lane & 15;

    const float* xb = x + (size_t)b * 270 * 2000;
    const float* x_last = x + (size_t)64 * 270 * 2000 - 4;

    f32x4 acc[6][4];
    #pragma unroll
    for (int m = 0; m < 6; ++m)
        #pragma unroll
        for (int n = 0; n < 4; ++n) acc[m][n] = (f32x4){0.f, 0.f, 0.f, 0.f};

    // stage k-tile ks into xs[buf]: wave wid stages rows {p*4+wid}, one GLL per row
    // LDS dest linear (lane*16B); swizzle applied on the GLOBAL source column.
    auto stage = [&](int buf, int ks) {
        #pragma unroll
        for (int p = 0; p < 8; ++p) {
            int row = p * 4 + wid;                       // wave-uniform
            int c = ks * 32 + row;
            if (c > 269) c = 269;                        // W k-pad is zero -> harmless
            int s = (row >> 2) & 7;
            const float* gp = xb + (size_t)c * 2000 + t0 + ((lane ^ s) << 2);
            if (gp > x_last) gp = x_last;                // in-bounds; masked at store
            __builtin_amdgcn_global_load_lds(
                (const __attribute__((address_space(1))) u32*)gp,
                (__attribute__((address_space(3))) u32*)&xs[buf][row][0],
                16, 0, 0);
        }
    };

    stage(0, 0);
    __syncthreads();

    for (int ks = 0; ks < 9; ++ks) {
        const int cur = ks & 1;
        if (ks < 8) stage(cur ^ 1, ks + 1);   // async into other buffer

        // A fragments (Wh/Wl rows o0..o0+95) straight from L1/L2
        bf16x8 ah[6], al[6];
        #pragma unroll
        for (int m = 0; m < 6; ++m) {
            int row = o0 + m * 16 + llo;
            size_t off = (size_t)row * 288 + ks * 32 + lhi * 8;
            ah[m] = *(const bf16x8*)(Wh + off);
            al[m] = *(const bf16x8*)(Wl + off);
        }

        #pragma unroll
        for (int nf = 0; nf < 4; ++nf) {
            int tcol = wt + nf * 16 + llo;
            float xr[8];
            #pragma unroll
            for (int j = 0; j < 8; ++j) {
                int k = lhi * 8 + j;
                int cidx = tcol ^ (((k >> 2) & 7) << 2);  // matches source swizzle
                xr[j] = xs[cur][k][cidx];
            }
            // in-register split to bf16 high/low fragments (truncation split)
            union { u32 u[4]; bf16x8 v; } bh, bl;
            #pragma unroll
            for (int p = 0; p < 4; ++p) {
                u32 u0 = __float_as_uint(xr[2 * p]);
                u32 u1 = __float_as_uint(xr[2 * p + 1]);
                bh.u[p] = (u0 >> 16) | (u1 & 0xFFFF0000u);
                float h0 = __uint_as_float(u0 & 0xFFFF0000u);
                float h1 = __uint_as_float(u1 & 0xFFFF0000u);
                u32 l0 = __float_as_uint(xr[2 * p] - h0);
                u32 l1 = __float_as_uint(xr[2 * p + 1] - h1);
                bl.u[p] = (l0 >> 16) | (l1 & 0xFFFF0000u);
            }
            #pragma unroll
            for (int m = 0; m < 6; ++m) {
                acc[m][nf] = __builtin_amdgcn_mfma_f32_16x16x32_bf16(ah[m], bh.v, acc[m][nf], 0, 0, 0);
                acc[m][nf] = __builtin_amdgcn_mfma_f32_16x16x32_bf16(ah[m], bl.v, acc[m][nf], 0, 0, 0);
                acc[m][nf] = __builtin_amdgcn_mfma_f32_16x16x32_bf16(al[m], bh.v, acc[m][nf], 0, 0, 0);
            }
        }

        __syncthreads();   // drains GLL (vmcnt 0) + readers done before overwrite
    }

    // epilogue: D frag -> out; D[row=4*lhi+r][col=llo]
    const size_t ob_base = (size_t)b * 270 * 2000;
    #pragma unroll
    for (int m = 0; m < 6; ++m) {
        #pragma unroll
        for (int r = 0; r < 4; ++r) {
            int orow = o0 + m * 16 + lhi * 4 + r;
            if (orow < 270) {
                float* op = out + ob_base + (size_t)orow * 2000;
                #pragma unroll
                for (int nf = 0; nf < 4; ++nf) {
                    int t = t0 + wt + nf * 16 + llo;
                    if (t < 2000) op[t] = acc[m][nf][r];
                }
            }
        }
    }
}

extern "C" void kernel_launch(void* const* d_in, const int* in_sizes, int n_in,
                              void* d_out, int out_size, void* d_ws, size_t ws_size,
                              hipStream_t stream) {
    const float* x      = (const float*)d_in[0];
    const float* layout = (const float*)d_in[1];
    const float* heads  = (const float*)d_in[2];
    float* out = (float*)d_out;
    char* ws = (char*)d_ws;

    float* scores          = (float*)(ws + SCORES_OFF);
    unsigned short* Wh     = (unsigned short*)(ws + WH_OFF);
    unsigned short* Wl     = (unsigned short*)(ws + WL_OFF);
    unsigned short* embh   = (unsigned short*)(ws + EMBH_OFF);
    unsigned short* headsh = (unsigned short*)(ws + HEADSH_OFF);

    prep_kernel<<<540, 256, 0, stream>>>(layout, heads, embh, headsh);
    scores_kernel<<<dim3(9, 9), 256, 0, stream>>>(headsh, embh, scores);
    softmax_kernel<<<288, 64, 0, stream>>>(scores, layout, Wh, Wl);
    merge_kernel<<<dim3(8, 3, 64), 256, 0, stream>>>(x, Wh, Wl, out);
}